// Round 1
// baseline (443.569 us; speedup 1.0000x reference)
//
#include <hip/hip_runtime.h>

// GraphormerAttention on MI355X — Round 1: correct fp32 baseline.
// Structure: bins(u8) -> QKV proj GEMMs (head-major out) -> flash attention
// with z-bias -> output proj GEMM. All fp32 vector math (no MFMA yet; fp32
// MFMA doesn't exist on CDNA4 — bf16/MFMA conversion is the round-2 lever).

#define NTOK  2048
#define DM    512
#define NH    8
#define DH    64
#define NBINS 16

// ---------------------------------------------------------------- bins ----
__device__ __forceinline__ int z_to_bin(float z) {
    // match jnp: clip(floor(z / MAX_Z * NUM_Z_BINS), 0, 15) — same op order
    int b = (int)floorf(z / 5.0f * 16.0f);
    return b < 0 ? 0 : (b > 15 ? 15 : b);
}

__global__ __launch_bounds__(256)
void bins_kernel(const float* __restrict__ z, unsigned char* __restrict__ bins) {
    int i = (blockIdx.x * 256 + threadIdx.x) * 4;   // exact fit: 2048*2048/4/256 = 4096 blocks
    float4 zv = *reinterpret_cast<const float4*>(z + i);
    uchar4 b;
    b.x = (unsigned char)z_to_bin(zv.x);
    b.y = (unsigned char)z_to_bin(zv.y);
    b.z = (unsigned char)z_to_bin(zv.z);
    b.w = (unsigned char)z_to_bin(zv.w);
    *reinterpret_cast<uchar4*>(bins + i) = b;
}

// ---------------------------------------------------------------- GEMM ----
// C[M=2048, N=512] = A[2048,512] @ W[512,512] + bias[512]
// HEADMAJOR: write C to out[(n>>6)][m][n&63]  (i.e. [h][tok][d], per-head contiguous)
// else:      write C to out[m][n]
// Block tile 64x64, BK=16, 256 threads, 4x4 micro-tile.
template<bool HEADMAJOR>
__global__ __launch_bounds__(256)
void gemm512(const float* __restrict__ A, const float* __restrict__ W,
             const float* __restrict__ bias, float* __restrict__ C) {
    const int n0 = blockIdx.x * 64;
    const int m0 = blockIdx.y * 64;
    const int t  = threadIdx.x;

    __shared__ float As[16][64 + 4];   // [k][m], padded: stride 68 breaks bank aliasing
    __shared__ float Ws[16][64 + 4];   // [k][n]

    const int r0 = (t >> 4) * 4;       // micro-tile rows   (0..60)
    const int c0 = (t & 15) * 4;       // micro-tile cols   (0..60)

    float acc[4][4] = {};

    for (int k0 = 0; k0 < DM; k0 += 16) {
        // -- stage A tile (64m x 16k) transposed into As[k][m]
        {
            const int m  = t >> 2;
            const int kq = (t & 3) * 4;
            float4 a4 = *reinterpret_cast<const float4*>(A + (size_t)(m0 + m) * DM + k0 + kq);
            As[kq + 0][m] = a4.x;
            As[kq + 1][m] = a4.y;
            As[kq + 2][m] = a4.z;
            As[kq + 3][m] = a4.w;
            // -- stage W tile (16k x 64n)
            const int kk = t >> 4;
            const int nq = (t & 15) * 4;
            float4 w4 = *reinterpret_cast<const float4*>(W + (size_t)(k0 + kk) * DM + n0 + nq);
            *reinterpret_cast<float4*>(&Ws[kk][nq]) = w4;
        }
        __syncthreads();

        #pragma unroll
        for (int k = 0; k < 16; ++k) {
            float a[4], w[4];
            float4 a4 = *reinterpret_cast<const float4*>(&As[k][r0]);
            float4 w4 = *reinterpret_cast<const float4*>(&Ws[k][c0]);
            a[0] = a4.x; a[1] = a4.y; a[2] = a4.z; a[3] = a4.w;
            w[0] = w4.x; w[1] = w4.y; w[2] = w4.z; w[3] = w4.w;
            #pragma unroll
            for (int i = 0; i < 4; ++i)
                #pragma unroll
                for (int j = 0; j < 4; ++j)
                    acc[i][j] += a[i] * w[j];
        }
        __syncthreads();
    }

    #pragma unroll
    for (int i = 0; i < 4; ++i) {
        const int m = m0 + r0 + i;
        #pragma unroll
        for (int j = 0; j < 4; ++j) {
            const int n = n0 + c0 + j;
            const float v = acc[i][j] + bias[n];
            if (HEADMAJOR) {
                const int h = n >> 6, d = n & 63;
                C[((size_t)h * NTOK + m) * DH + d] = v;
            } else {
                C[(size_t)m * DM + n] = v;
            }
        }
    }
}

// ----------------------------------------------------------- attention ----
// grid (32 qtiles, 8 heads), 256 threads. QT=KT=64. Flash-style online softmax.
// q_ws/k_ws/v_ws: [h][tok][d] fp32. bins: [n][m] u8. o_ws: [tok][DM] fp32.
__global__ __launch_bounds__(256)
void attn_kernel(const float* __restrict__ q_ws, const float* __restrict__ k_ws,
                 const float* __restrict__ v_ws, const unsigned char* __restrict__ bins,
                 const float* __restrict__ z_table, float* __restrict__ o_ws) {
    const int h    = blockIdx.y;
    const int q0   = blockIdx.x * 64;
    const int t    = threadIdx.x;
    const int w    = t >> 6;
    const int lane = t & 63;
    const int rg   = lane >> 4;            // 0..3 (16-lane row group — shfl-reducible)
    const int r0   = w * 16 + rg * 4;      // this thread's 4 score/output rows
    const int c0   = (lane & 15) * 4;      // 4 score cols == 4 output dims

    __shared__ float Qs[64][DH + 4];       // padded: row stride 68 words
    __shared__ float Ks[64][DH + 4];
    __shared__ float Vs[64][DH];           // read pattern is conflict-free unpadded
    __shared__ float Ps[64][64 + 4];
    __shared__ unsigned char Bs[64][64];
    __shared__ float ztab[NBINS];

    if (t < NBINS) ztab[t] = z_table[t * NH + h];

    // stage Q tile once
    {
        const float* Qg = q_ws + ((size_t)h * NTOK + q0) * DH;
        #pragma unroll
        for (int i = 0; i < 4; ++i) {
            const int f = t + i * 256;
            const int r = f >> 4, c4 = (f & 15) * 4;
            *reinterpret_cast<float4*>(&Qs[r][c4]) =
                *reinterpret_cast<const float4*>(Qg + r * DH + c4);
        }
    }

    float m_run[4], l_run[4];
    float acc[4][4] = {};
    #pragma unroll
    for (int i = 0; i < 4; ++i) { m_run[i] = -1e30f; l_run[i] = 0.0f; }

    const float scale = 0.125f;  // HEAD_DIM^-0.5

    for (int kt = 0; kt < NTOK; kt += 64) {
        __syncthreads();   // prev-iter LDS reads done (also covers Q staging, iter 0)

        // -- stage K, V, bins tiles
        const float* Kg = k_ws + ((size_t)h * NTOK + kt) * DH;
        const float* Vg = v_ws + ((size_t)h * NTOK + kt) * DH;
        #pragma unroll
        for (int i = 0; i < 4; ++i) {
            const int f = t + i * 256;
            const int r = f >> 4, c4 = (f & 15) * 4;
            *reinterpret_cast<float4*>(&Ks[r][c4]) =
                *reinterpret_cast<const float4*>(Kg + r * DH + c4);
            *reinterpret_cast<float4*>(&Vs[r][c4]) =
                *reinterpret_cast<const float4*>(Vg + r * DH + c4);
            *reinterpret_cast<uchar4*>(&Bs[r][c4]) =
                *reinterpret_cast<const uchar4*>(bins + (size_t)(q0 + r) * NTOK + kt + c4);
        }
        __syncthreads();

        // -- S = Q Kᵀ  (4x4 per thread, fp32)
        float s[4][4] = {};
        #pragma unroll 4
        for (int d4 = 0; d4 < DH; d4 += 4) {
            float qv[4][4], kv[4][4];
            #pragma unroll
            for (int i = 0; i < 4; ++i) {
                float4 v4 = *reinterpret_cast<const float4*>(&Qs[r0 + i][d4]);
                qv[i][0] = v4.x; qv[i][1] = v4.y; qv[i][2] = v4.z; qv[i][3] = v4.w;
            }
            #pragma unroll
            for (int j = 0; j < 4; ++j) {
                float4 v4 = *reinterpret_cast<const float4*>(&Ks[c0 + j][d4]);
                kv[j][0] = v4.x; kv[j][1] = v4.y; kv[j][2] = v4.z; kv[j][3] = v4.w;
            }
            #pragma unroll
            for (int i = 0; i < 4; ++i)
                #pragma unroll
                for (int j = 0; j < 4; ++j)
                    s[i][j] += qv[i][0]*kv[j][0] + qv[i][1]*kv[j][1]
                             + qv[i][2]*kv[j][2] + qv[i][3]*kv[j][3];
        }
        // scale + z-bias
        #pragma unroll
        for (int i = 0; i < 4; ++i)
            #pragma unroll
            for (int j = 0; j < 4; ++j)
                s[i][j] = s[i][j] * scale + ztab[Bs[r0 + i][c0 + j]];

        // -- online softmax (rows live in 16 contiguous lanes -> shfl_xor reduce)
        #pragma unroll
        for (int i = 0; i < 4; ++i) {
            float tm = fmaxf(fmaxf(s[i][0], s[i][1]), fmaxf(s[i][2], s[i][3]));
            #pragma unroll
            for (int off = 1; off < 16; off <<= 1)
                tm = fmaxf(tm, __shfl_xor(tm, off, 64));
            const float mn = fmaxf(m_run[i], tm);
            const float ef = __expf(m_run[i] - mn);
            m_run[i] = mn;
            float p[4], ts = 0.0f;
            #pragma unroll
            for (int j = 0; j < 4; ++j) { p[j] = __expf(s[i][j] - mn); ts += p[j]; }
            #pragma unroll
            for (int off = 1; off < 16; off <<= 1)
                ts += __shfl_xor(ts, off, 64);
            l_run[i] = l_run[i] * ef + ts;
            #pragma unroll
            for (int j = 0; j < 4; ++j) acc[i][j] *= ef;
            *reinterpret_cast<float4*>(&Ps[r0 + i][c0]) = make_float4(p[0], p[1], p[2], p[3]);
        }
        __syncthreads();   // P visible to all lanes

        // -- acc += P · V   (over this key tile)
        #pragma unroll 4
        for (int m4 = 0; m4 < 64; m4 += 4) {
            float pv[4][4], vv[4][4];
            #pragma unroll
            for (int i = 0; i < 4; ++i) {
                float4 v4 = *reinterpret_cast<const float4*>(&Ps[r0 + i][m4]);
                pv[i][0] = v4.x; pv[i][1] = v4.y; pv[i][2] = v4.z; pv[i][3] = v4.w;
            }
            #pragma unroll
            for (int mm = 0; mm < 4; ++mm) {
                float4 v4 = *reinterpret_cast<const float4*>(&Vs[m4 + mm][c0]);
                vv[mm][0] = v4.x; vv[mm][1] = v4.y; vv[mm][2] = v4.z; vv[mm][3] = v4.w;
            }
            #pragma unroll
            for (int i = 0; i < 4; ++i)
                #pragma unroll
                for (int dd = 0; dd < 4; ++dd)
                    acc[i][dd] += pv[i][0]*vv[0][dd] + pv[i][1]*vv[1][dd]
                                + pv[i][2]*vv[2][dd] + pv[i][3]*vv[3][dd];
        }
    }

    // -- epilogue: normalize, write [tok][DM] with col = h*64 + dim
    #pragma unroll
    for (int i = 0; i < 4; ++i) {
        const float inv = 1.0f / l_run[i];
        float4 o = make_float4(acc[i][0]*inv, acc[i][1]*inv, acc[i][2]*inv, acc[i][3]*inv);
        *reinterpret_cast<float4*>(o_ws + (size_t)(q0 + r0 + i) * DM + h * DH + c0) = o;
    }
}

// --------------------------------------------------------------- launch ----
extern "C" void kernel_launch(void* const* d_in, const int* in_sizes, int n_in,
                              void* d_out, int out_size, void* d_ws, size_t ws_size,
                              hipStream_t stream) {
    const float* x        = (const float*)d_in[0];
    const float* z_matrix = (const float*)d_in[1];
    const float* Wq       = (const float*)d_in[2];
    const float* bq       = (const float*)d_in[3];
    const float* Wk       = (const float*)d_in[4];
    const float* bk       = (const float*)d_in[5];
    const float* Wv       = (const float*)d_in[6];
    const float* bv       = (const float*)d_in[7];
    const float* Wo       = (const float*)d_in[8];
    const float* bo       = (const float*)d_in[9];
    const float* z_table  = (const float*)d_in[10];
    float* out            = (float*)d_out;

    // workspace layout (needs ~20.2 MB)
    float* q_ws = (float*)d_ws;                       // [8][2048][64]  4 MB
    float* k_ws = q_ws + (size_t)NH * NTOK * DH;      // 4 MB
    float* v_ws = k_ws + (size_t)NH * NTOK * DH;      // 4 MB
    float* o_ws = v_ws + (size_t)NH * NTOK * DH;      // [2048][512]    4 MB
    unsigned char* bins = (unsigned char*)(o_ws + (size_t)NTOK * DM);  // 4.2 MB

    // 1) bins
    bins_kernel<<<dim3(NTOK * NTOK / 4 / 256), dim3(256), 0, stream>>>(z_matrix, bins);

    // 2) QKV projections (head-major outputs)
    dim3 ggrid(DM / 64, NTOK / 64);
    gemm512<true><<<ggrid, dim3(256), 0, stream>>>(x, Wq, bq, q_ws);
    gemm512<true><<<ggrid, dim3(256), 0, stream>>>(x, Wk, bk, k_ws);
    gemm512<true><<<ggrid, dim3(256), 0, stream>>>(x, Wv, bv, v_ws);

    // 3) attention
    attn_kernel<<<dim3(NTOK / 64, NH), dim3(256), 0, stream>>>(
        q_ws, k_ws, v_ws, bins, z_table, o_ws);

    // 4) output projection
    gemm512<false><<<ggrid, dim3(256), 0, stream>>>(o_ws, Wo, bo, out);
}

// Round 3
// 329.613 us; speedup vs baseline: 1.3457x; 1.3457x over previous
//
#include <hip/hip_runtime.h>

// GraphormerAttention on MI355X — Round 3 (= R2 resubmit; broker timed out).
// Changes vs R1 (443 µs total; attn 270 µs @ VALUBusy 39%, occupancy 11%):
//  * attn: KV-split S=2 (grid 512 -> 2 blocks/CU -> 2 waves/SIMD), lane-contiguous
//    K-row reads (kills the 8-way LDS bank conflict on Ks), partial O/m/l + merge.
//  * QKV projections fused into one launch (768 blocks -> 3 blocks/CU).
//  * Wo GEMM re-tiled 32x64 (512 blocks -> 2 blocks/CU).
//  * (new this round) Qs padded to DH+4: QK^T q-row reads were 4-way bank conflict.

#define NTOK   2048
#define DM     512
#define NH     8
#define DH     64
#define NBINS  16
#define NSPLIT 2
#define KPS    (NTOK / NSPLIT)   // keys per split = 1024

// ---------------------------------------------------------------- bins ----
__device__ __forceinline__ int z_to_bin(float z) {
    int b = (int)floorf(z / 5.0f * 16.0f);   // match jnp op order exactly
    return b < 0 ? 0 : (b > 15 ? 15 : b);
}

__global__ __launch_bounds__(256)
void bins_kernel(const float* __restrict__ z, unsigned char* __restrict__ bins) {
    int i = (blockIdx.x * 256 + threadIdx.x) * 4;   // 4096 blocks, exact fit
    float4 zv = *reinterpret_cast<const float4*>(z + i);
    uchar4 b;
    b.x = (unsigned char)z_to_bin(zv.x);
    b.y = (unsigned char)z_to_bin(zv.y);
    b.z = (unsigned char)z_to_bin(zv.z);
    b.w = (unsigned char)z_to_bin(zv.w);
    *reinterpret_cast<uchar4*>(bins + i) = b;
}

// ------------------------------------------------------------ QKV GEMM ----
// C[2048,512] = A @ W + b, head-major out [h][tok][d]. blockIdx.z picks Q/K/V.
// 64x64 tile, BK=16, 256 threads, 4x4 micro. grid (8, 32, 3) = 768 blocks.
__global__ __launch_bounds__(256)
void qkv_gemm(const float* __restrict__ A,
              const float* __restrict__ Wq, const float* __restrict__ Wk,
              const float* __restrict__ Wv,
              const float* __restrict__ bq, const float* __restrict__ bk,
              const float* __restrict__ bv,
              float* __restrict__ Oq, float* __restrict__ Ok, float* __restrict__ Ov) {
    const int which = blockIdx.z;
    const float* __restrict__ W    = which == 0 ? Wq : which == 1 ? Wk : Wv;
    const float* __restrict__ bias = which == 0 ? bq : which == 1 ? bk : bv;
    float* __restrict__ C          = which == 0 ? Oq : which == 1 ? Ok : Ov;

    const int n0 = blockIdx.x * 64;
    const int m0 = blockIdx.y * 64;
    const int t  = threadIdx.x;

    __shared__ float As[16][64 + 4];
    __shared__ float Ws[16][64 + 4];

    const int r0 = (t >> 4) * 4;
    const int c0 = (t & 15) * 4;

    float acc[4][4] = {};

    for (int k0 = 0; k0 < DM; k0 += 16) {
        {
            const int m  = t >> 2;
            const int kq = (t & 3) * 4;
            float4 a4 = *reinterpret_cast<const float4*>(A + (size_t)(m0 + m) * DM + k0 + kq);
            As[kq + 0][m] = a4.x;
            As[kq + 1][m] = a4.y;
            As[kq + 2][m] = a4.z;
            As[kq + 3][m] = a4.w;
            const int kk = t >> 4;
            const int nq = (t & 15) * 4;
            *reinterpret_cast<float4*>(&Ws[kk][nq]) =
                *reinterpret_cast<const float4*>(W + (size_t)(k0 + kk) * DM + n0 + nq);
        }
        __syncthreads();

        #pragma unroll
        for (int k = 0; k < 16; ++k) {
            float4 a4 = *reinterpret_cast<const float4*>(&As[k][r0]);
            float4 w4 = *reinterpret_cast<const float4*>(&Ws[k][c0]);
            float a[4] = {a4.x, a4.y, a4.z, a4.w};
            float w[4] = {w4.x, w4.y, w4.z, w4.w};
            #pragma unroll
            for (int i = 0; i < 4; ++i)
                #pragma unroll
                for (int j = 0; j < 4; ++j)
                    acc[i][j] += a[i] * w[j];
        }
        __syncthreads();
    }

    #pragma unroll
    for (int i = 0; i < 4; ++i) {
        const int m = m0 + r0 + i;
        #pragma unroll
        for (int j = 0; j < 4; ++j) {
            const int n = n0 + c0 + j;
            const int h = n >> 6, d = n & 63;
            C[((size_t)h * NTOK + m) * DH + d] = acc[i][j] + bias[n];
        }
    }
}

// -------------------------------------------------------------- Wo GEMM ----
// out[2048,512] = o_ws @ Wo + bo. 32x64 tile, 256 threads, 2x4 micro.
// grid (8 n-tiles, 64 m-tiles) = 512 blocks -> 2 blocks/CU.
__global__ __launch_bounds__(256)
void wo_gemm(const float* __restrict__ A, const float* __restrict__ W,
             const float* __restrict__ bias, float* __restrict__ C) {
    const int n0 = blockIdx.x * 64;
    const int m0 = blockIdx.y * 32;
    const int t  = threadIdx.x;

    __shared__ float As[16][32 + 4];
    __shared__ float Ws[16][64 + 4];

    const int r0 = (t >> 4) * 2;       // 0..30
    const int c0 = (t & 15) * 4;       // 0..60

    float acc[2][4] = {};

    for (int k0 = 0; k0 < DM; k0 += 16) {
        if (t < 128) {                 // A tile: 32 rows x 16 k = 128 float4
            const int m  = t >> 2;
            const int kq = (t & 3) * 4;
            float4 a4 = *reinterpret_cast<const float4*>(A + (size_t)(m0 + m) * DM + k0 + kq);
            As[kq + 0][m] = a4.x;
            As[kq + 1][m] = a4.y;
            As[kq + 2][m] = a4.z;
            As[kq + 3][m] = a4.w;
        }
        {
            const int kk = t >> 4;
            const int nq = (t & 15) * 4;
            *reinterpret_cast<float4*>(&Ws[kk][nq]) =
                *reinterpret_cast<const float4*>(W + (size_t)(k0 + kk) * DM + n0 + nq);
        }
        __syncthreads();

        #pragma unroll
        for (int k = 0; k < 16; ++k) {
            float2 a2 = *reinterpret_cast<const float2*>(&As[k][r0]);
            float4 w4 = *reinterpret_cast<const float4*>(&Ws[k][c0]);
            float a[2] = {a2.x, a2.y};
            float w[4] = {w4.x, w4.y, w4.z, w4.w};
            #pragma unroll
            for (int i = 0; i < 2; ++i)
                #pragma unroll
                for (int j = 0; j < 4; ++j)
                    acc[i][j] += a[i] * w[j];
        }
        __syncthreads();
    }

    #pragma unroll
    for (int i = 0; i < 2; ++i) {
        float4 b4 = *reinterpret_cast<const float4*>(bias + n0 + c0);
        float4 o  = make_float4(acc[i][0] + b4.x, acc[i][1] + b4.y,
                                acc[i][2] + b4.z, acc[i][3] + b4.w);
        *reinterpret_cast<float4*>(C + (size_t)(m0 + r0 + i) * DM + n0 + c0) = o;
    }
}

// ----------------------------------------------------------- attention ----
// grid (32 qtiles, 8 heads, NSPLIT). 256 threads. QT=64, KT=64.
// Writes UNNORMALIZED partial O + running (m, l) per row per split.
// Score cols per thread: c = (lane&15) + 16*j  -> K-row LDS reads are 16
// CONSECUTIVE rows at stride 68 words => minimal bank serialization.
__global__ __launch_bounds__(256)
void attn_kernel(const float* __restrict__ q_ws, const float* __restrict__ k_ws,
                 const float* __restrict__ v_ws, const unsigned char* __restrict__ bins,
                 const float* __restrict__ z_table,
                 float* __restrict__ po, float* __restrict__ pm, float* __restrict__ pl) {
    const int h    = blockIdx.y;
    const int q0   = blockIdx.x * 64;
    const int z    = blockIdx.z;
    const int t    = threadIdx.x;
    const int w    = t >> 6;
    const int lane = t & 63;
    const int rg   = lane >> 4;
    const int cb   = lane & 15;            // score-col base; also output-dim group
    const int r0   = w * 16 + rg * 4;      // 4 rows per thread
    const int c0v  = cb * 4;               // 4 output dims per thread

    __shared__ float Qs[64][DH + 4];       // padded: q-row reads were 4-way conflict
    __shared__ float Ks[64][DH + 4];       // stride 68: consecutive-row b128 reads spread banks
    __shared__ float Vs[64][DH];           // same-row b128 reads: minimal (2-way)
    __shared__ float Ps[64][DH + 4];
    __shared__ unsigned char Bs[64][64];
    __shared__ float ztab[NBINS];

    if (t < NBINS) ztab[t] = z_table[t * NH + h];

    {   // stage Q tile once
        const float* Qg = q_ws + ((size_t)h * NTOK + q0) * DH;
        #pragma unroll
        for (int i = 0; i < 4; ++i) {
            const int f = t + i * 256;
            const int r = f >> 4, c4 = (f & 15) * 4;
            *reinterpret_cast<float4*>(&Qs[r][c4]) =
                *reinterpret_cast<const float4*>(Qg + r * DH + c4);
        }
    }

    float m_run[4], l_run[4];
    float acc[4][4] = {};
    #pragma unroll
    for (int i = 0; i < 4; ++i) { m_run[i] = -1e30f; l_run[i] = 0.0f; }

    const float scale = 0.125f;
    const int   kbase = z * KPS;

    for (int kt = 0; kt < KPS; kt += 64) {
        __syncthreads();   // prev-iter LDS reads done (also covers Q/ztab staging, iter 0)

        const float* Kg = k_ws + ((size_t)h * NTOK + kbase + kt) * DH;
        const float* Vg = v_ws + ((size_t)h * NTOK + kbase + kt) * DH;
        #pragma unroll
        for (int i = 0; i < 4; ++i) {
            const int f = t + i * 256;
            const int r = f >> 4, c4 = (f & 15) * 4;
            *reinterpret_cast<float4*>(&Ks[r][c4]) =
                *reinterpret_cast<const float4*>(Kg + r * DH + c4);
            *reinterpret_cast<float4*>(&Vs[r][c4]) =
                *reinterpret_cast<const float4*>(Vg + r * DH + c4);
            *reinterpret_cast<uchar4*>(&Bs[r][c4]) =
                *reinterpret_cast<const uchar4*>(bins + (size_t)(q0 + r) * NTOK + kbase + kt + c4);
        }
        __syncthreads();

        // -- S = Q K^T : s[i][j] is score (row r0+i, col cb + 16j)
        float s[4][4] = {};
        #pragma unroll 4
        for (int d4 = 0; d4 < DH; d4 += 4) {
            float qv[4][4], kv[4][4];
            #pragma unroll
            for (int i = 0; i < 4; ++i) {
                float4 v4 = *reinterpret_cast<const float4*>(&Qs[r0 + i][d4]);
                qv[i][0] = v4.x; qv[i][1] = v4.y; qv[i][2] = v4.z; qv[i][3] = v4.w;
            }
            #pragma unroll
            for (int j = 0; j < 4; ++j) {
                float4 v4 = *reinterpret_cast<const float4*>(&Ks[cb + 16 * j][d4]);
                kv[j][0] = v4.x; kv[j][1] = v4.y; kv[j][2] = v4.z; kv[j][3] = v4.w;
            }
            #pragma unroll
            for (int i = 0; i < 4; ++i)
                #pragma unroll
                for (int j = 0; j < 4; ++j)
                    s[i][j] += qv[i][0]*kv[j][0] + qv[i][1]*kv[j][1]
                             + qv[i][2]*kv[j][2] + qv[i][3]*kv[j][3];
        }
        #pragma unroll
        for (int i = 0; i < 4; ++i)
            #pragma unroll
            for (int j = 0; j < 4; ++j)
                s[i][j] = s[i][j] * scale + ztab[Bs[r0 + i][cb + 16 * j]];

        // -- online softmax (row spread over 16 lanes, 4 cols each)
        #pragma unroll
        for (int i = 0; i < 4; ++i) {
            float tm = fmaxf(fmaxf(s[i][0], s[i][1]), fmaxf(s[i][2], s[i][3]));
            #pragma unroll
            for (int off = 1; off < 16; off <<= 1)
                tm = fmaxf(tm, __shfl_xor(tm, off, 64));
            const float mn = fmaxf(m_run[i], tm);
            const float ef = __expf(m_run[i] - mn);
            m_run[i] = mn;
            float p[4], ts = 0.0f;
            #pragma unroll
            for (int j = 0; j < 4; ++j) { p[j] = __expf(s[i][j] - mn); ts += p[j]; }
            #pragma unroll
            for (int off = 1; off < 16; off <<= 1)
                ts += __shfl_xor(ts, off, 64);
            l_run[i] = l_run[i] * ef + ts;
            #pragma unroll
            for (int j = 0; j < 4; ++j) acc[i][j] *= ef;
            #pragma unroll
            for (int j = 0; j < 4; ++j) Ps[r0 + i][cb + 16 * j] = p[j];
        }
        __syncthreads();   // P visible to all lanes

        // -- acc += P · V
        #pragma unroll 4
        for (int m4 = 0; m4 < 64; m4 += 4) {
            float pv[4][4], vv[4][4];
            #pragma unroll
            for (int i = 0; i < 4; ++i) {
                float4 v4 = *reinterpret_cast<const float4*>(&Ps[r0 + i][m4]);
                pv[i][0] = v4.x; pv[i][1] = v4.y; pv[i][2] = v4.z; pv[i][3] = v4.w;
            }
            #pragma unroll
            for (int mm = 0; mm < 4; ++mm) {
                float4 v4 = *reinterpret_cast<const float4*>(&Vs[m4 + mm][c0v]);
                vv[mm][0] = v4.x; vv[mm][1] = v4.y; vv[mm][2] = v4.z; vv[mm][3] = v4.w;
            }
            #pragma unroll
            for (int i = 0; i < 4; ++i)
                #pragma unroll
                for (int dd = 0; dd < 4; ++dd)
                    acc[i][dd] += pv[i][0]*vv[0][dd] + pv[i][1]*vv[1][dd]
                                + pv[i][2]*vv[2][dd] + pv[i][3]*vv[3][dd];
        }
    }

    // -- partial epilogue: unnormalized O + (m, l)
    #pragma unroll
    for (int i = 0; i < 4; ++i) {
        const size_t row = (size_t)(z * NH + h) * NTOK + q0 + r0 + i;
        *reinterpret_cast<float4*>(po + row * DH + c0v) =
            make_float4(acc[i][0], acc[i][1], acc[i][2], acc[i][3]);
        if (cb == 0) { pm[row] = m_run[i]; pl[row] = l_run[i]; }
    }
}

// --------------------------------------------------------------- merge ----
// Combine the NSPLIT partials: O = sum_s e^{m_s - M} O_s ; L = sum_s e^{m_s - M} l_s.
__global__ __launch_bounds__(256)
void merge_kernel(const float* __restrict__ po, const float* __restrict__ pm,
                  const float* __restrict__ pl, float* __restrict__ o_ws) {
    const int e = (blockIdx.x * 256 + threadIdx.x) * 4;   // 1024 blocks, exact fit
    const int d = e & (DH - 1);
    const int n = (e >> 6) & (NTOK - 1);
    const int h = e >> 17;

    const size_t r1 = (size_t)h * NTOK + n;               // split 0
    const size_t r2 = (size_t)(NH + h) * NTOK + n;        // split 1
    const float m1 = pm[r1], m2 = pm[r2];
    const float M  = fmaxf(m1, m2);
    const float w1 = __expf(m1 - M), w2 = __expf(m2 - M);
    const float L  = pl[r1] * w1 + pl[r2] * w2;
    const float inv = 1.0f / L;

    float4 o1 = *reinterpret_cast<const float4*>(po + r1 * DH + d);
    float4 o2 = *reinterpret_cast<const float4*>(po + r2 * DH + d);
    float4 o = make_float4((o1.x * w1 + o2.x * w2) * inv,
                           (o1.y * w1 + o2.y * w2) * inv,
                           (o1.z * w1 + o2.z * w2) * inv,
                           (o1.w * w1 + o2.w * w2) * inv);
    *reinterpret_cast<float4*>(o_ws + (size_t)n * DM + h * DH + d) = o;
}

// --------------------------------------------------------------- launch ----
extern "C" void kernel_launch(void* const* d_in, const int* in_sizes, int n_in,
                              void* d_out, int out_size, void* d_ws, size_t ws_size,
                              hipStream_t stream) {
    const float* x        = (const float*)d_in[0];
    const float* z_matrix = (const float*)d_in[1];
    const float* Wq       = (const float*)d_in[2];
    const float* bq       = (const float*)d_in[3];
    const float* Wk       = (const float*)d_in[4];
    const float* bk       = (const float*)d_in[5];
    const float* Wv       = (const float*)d_in[6];
    const float* bv       = (const float*)d_in[7];
    const float* Wo       = (const float*)d_in[8];
    const float* bo       = (const float*)d_in[9];
    const float* z_table  = (const float*)d_in[10];
    float* out            = (float*)d_out;

    // workspace (~24.3 MB): q|k|v [8][2048][64] (12MB), po [2][8][2048][64] (8MB),
    // pm|pl (256KB), bins (4MB; o_ws aliases bins after attention is done)
    const size_t HTD = (size_t)NH * NTOK * DH;
    float* q_ws = (float*)d_ws;
    float* k_ws = q_ws + HTD;
    float* v_ws = k_ws + HTD;
    float* po   = v_ws + HTD;
    float* pm   = po + (size_t)NSPLIT * HTD;
    float* pl   = pm + (size_t)NSPLIT * NH * NTOK;
    unsigned char* bins = (unsigned char*)(pl + (size_t)NSPLIT * NH * NTOK);
    float* o_ws = (float*)bins;   // alias: bins dead once attention completes

    bins_kernel<<<dim3(NTOK * NTOK / 4 / 256), dim3(256), 0, stream>>>(z_matrix, bins);

    qkv_gemm<<<dim3(DM / 64, NTOK / 64, 3), dim3(256), 0, stream>>>(
        x, Wq, Wk, Wv, bq, bk, bv, q_ws, k_ws, v_ws);

    attn_kernel<<<dim3(NTOK / 64, NH, NSPLIT), dim3(256), 0, stream>>>(
        q_ws, k_ws, v_ws, bins, z_table, po, pm, pl);

    merge_kernel<<<dim3(NH * NTOK * DH / 4 / 256), dim3(256), 0, stream>>>(
        po, pm, pl, o_ws);

    wo_gemm<<<dim3(DM / 64, NTOK / 32), dim3(256), 0, stream>>>(o_ws, Wo, bo, out);
}

// Round 5
// 174.514 us; speedup vs baseline: 2.5417x; 1.8887x over previous
//
#include <hip/hip_runtime.h>

// GraphormerAttention on MI355X — Round 5 (= R4 resubmit; broker timed out).
// Split-bf16 (hi+lo) MFMA everywhere: QKV proj, QK^T, PV, Wo all on
// v_mfma_f32_32x32x16_bf16, 3 MFMAs per product (hi*hi + hi*lo + lo*hi).
// R3 fp32 vector path: 329 us, issue-bound (157 TF ceiling). MFMA: 2382 TF.
//
// Verified layout facts used (learn_hip m74/m101): 32x32x16 C/D mapping
//   row = (reg&3) + 8*(reg>>2) + 4*(lane>>5),  col = lane&31.
// A/B fragment slot map ASSUMED symmetric (A[row=l&31][k=8*(l>>5)+j],
// B[k=8*(l>>5)+j][col=l&31]) and used IDENTICALLY for every operand, so any
// HW k-permutation cancels (same bijection on both sides of every contraction,
// including PV whose A-frag is built in-register from the verified C/D map).

#define NTOK   2048
#define DM     512
#define NH     8
#define DH     64
#define NBINS  16
#define NSPLIT 4
#define KPS    (NTOK / NSPLIT)   // 512 keys per split

typedef float  f32x16 __attribute__((ext_vector_type(16)));
typedef short  short8 __attribute__((ext_vector_type(8)));
typedef unsigned short ushort_t;

#define MFMA32(A, B, C) __builtin_amdgcn_mfma_f32_32x32x16_bf16((A), (B), (C), 0, 0, 0)

__device__ __forceinline__ unsigned short f2bf(float x) {   // fp32 -> bf16 RNE
    union { float f; unsigned u; } v; v.f = x;
    unsigned r = v.u + 0x7FFFu + ((v.u >> 16) & 1u);
    return (unsigned short)(r >> 16);
}
__device__ __forceinline__ float bf2f(unsigned short b) {
    union { unsigned u; float f; } v; v.u = ((unsigned)b) << 16;
    return v.f;
}
// split x into hi+lo bf16 halves
__device__ __forceinline__ void splitbf(float x, unsigned short& hi, unsigned short& lo) {
    hi = f2bf(x);
    lo = f2bf(x - bf2f(hi));
}

union FragU { unsigned u[4]; short8 s; };

// ---------------------------------------------------------------- bins ----
__device__ __forceinline__ int z_to_bin(float z) {
    int b = (int)floorf(z / 5.0f * 16.0f);   // match jnp op order
    return b < 0 ? 0 : (b > 15 ? 15 : b);
}

__global__ __launch_bounds__(256)
void bins_kernel(const float* __restrict__ z, unsigned char* __restrict__ bins) {
    int i = (blockIdx.x * 256 + threadIdx.x) * 4;
    float4 zv = *reinterpret_cast<const float4*>(z + i);
    uchar4 b;
    b.x = (unsigned char)z_to_bin(zv.x);
    b.y = (unsigned char)z_to_bin(zv.y);
    b.z = (unsigned char)z_to_bin(zv.z);
    b.w = (unsigned char)z_to_bin(zv.w);
    *reinterpret_cast<uchar4*>(bins + i) = b;
}

// ------------------------------------------------------- prep: W -> W^T ----
// grid (16,16,4): transpose-convert Wq/Wk/Wv/Wo (512x512 f32, [k][n]) into
// WT hi/lo bf16 [n][k]. z block offset = z * 1 MB (DM*DM*2 ushorts).
__global__ __launch_bounds__(256)
void prep_w(const float* __restrict__ Wq, const float* __restrict__ Wk,
            const float* __restrict__ Wv, const float* __restrict__ Wo,
            ushort_t* __restrict__ wt_hi_base, ushort_t* __restrict__ wt_lo_base) {
    const int z = blockIdx.z;
    const float* __restrict__ W = z == 0 ? Wq : z == 1 ? Wk : z == 2 ? Wv : Wo;
    ushort_t* __restrict__ th = wt_hi_base + (size_t)z * DM * DM * 2;
    ushort_t* __restrict__ tl = wt_lo_base + (size_t)z * DM * DM * 2;

    const int r0 = blockIdx.y * 32;   // k rows of W
    const int c0 = blockIdx.x * 32;   // n cols of W
    const int t  = threadIdx.x;

    __shared__ float Tl[32][33];

    {
        const int r = t >> 3, c4 = (t & 7) * 4;
        float4 v = *reinterpret_cast<const float4*>(W + (size_t)(r0 + r) * DM + c0 + c4);
        Tl[r][c4 + 0] = v.x; Tl[r][c4 + 1] = v.y; Tl[r][c4 + 2] = v.z; Tl[r][c4 + 3] = v.w;
    }
    __syncthreads();
    {
        const int c = t >> 3, r4 = (t & 7) * 4;
        ushort_t h4[4], l4[4];
        #pragma unroll
        for (int k = 0; k < 4; ++k) splitbf(Tl[r4 + k][c], h4[k], l4[k]);
        *reinterpret_cast<ushort4*>(th + (size_t)(c0 + c) * DM + r0 + r4) =
            make_ushort4(h4[0], h4[1], h4[2], h4[3]);
        *reinterpret_cast<ushort4*>(tl + (size_t)(c0 + c) * DM + r0 + r4) =
            make_ushort4(l4[0], l4[1], l4[2], l4[3]);
    }
}

// ------------------------------------------------------- prep: x hi/lo ----
__global__ __launch_bounds__(256)
void conv_x(const float* __restrict__ x, ushort_t* __restrict__ xh, ushort_t* __restrict__ xl) {
    int i = (blockIdx.x * 256 + threadIdx.x) * 4;   // 1024 blocks
    float4 v = *reinterpret_cast<const float4*>(x + i);
    ushort_t h[4], l[4];
    splitbf(v.x, h[0], l[0]); splitbf(v.y, h[1], l[1]);
    splitbf(v.z, h[2], l[2]); splitbf(v.w, h[3], l[3]);
    *reinterpret_cast<ushort4*>(xh + i) = make_ushort4(h[0], h[1], h[2], h[3]);
    *reinterpret_cast<ushort4*>(xl + i) = make_ushort4(l[0], l[1], l[2], l[3]);
}

// ----------------------------------------------------------- QKV GEMM ----
// C[2048,512] = x @ W + b via split-bf16 MFMA. Block 64x64, BK=32, 4 waves
// (2x2 of 32x32). z picks Q/K/V. Q,K out: [h][tok][d] hi/lo. V out: [h][d][tok].
__global__ __launch_bounds__(256, 3)
void qkv_gemm_mfma(const ushort_t* __restrict__ x_hi, const ushort_t* __restrict__ x_lo,
                   const ushort_t* __restrict__ wqt_hi, const ushort_t* __restrict__ wqt_lo,
                   const ushort_t* __restrict__ wkt_hi, const ushort_t* __restrict__ wkt_lo,
                   const ushort_t* __restrict__ wvt_hi, const ushort_t* __restrict__ wvt_lo,
                   const float* __restrict__ bq, const float* __restrict__ bk,
                   const float* __restrict__ bv,
                   ushort_t* __restrict__ q_hi, ushort_t* __restrict__ q_lo,
                   ushort_t* __restrict__ k_hi, ushort_t* __restrict__ k_lo,
                   ushort_t* __restrict__ vT_hi, ushort_t* __restrict__ vT_lo) {
    const int z = blockIdx.z;
    const ushort_t* __restrict__ bt_hi = z == 0 ? wqt_hi : z == 1 ? wkt_hi : wvt_hi;
    const ushort_t* __restrict__ bt_lo = z == 0 ? wqt_lo : z == 1 ? wkt_lo : wvt_lo;
    const float*    __restrict__ bias  = z == 0 ? bq : z == 1 ? bk : bv;

    const int n0 = blockIdx.x * 64;
    const int m0 = blockIdx.y * 64;
    const int t  = threadIdx.x;
    const int wid = t >> 6, l = t & 63, hf = l >> 5, lq = l & 31;
    const int wm = wid >> 1, wn = wid & 1;

    // LDS: rows padded to 40 ushort (80 B, 16B-multiple) for bank spread
    __shared__ __align__(16) ushort_t Ash_hi[64 * 40], Ash_lo[64 * 40];
    __shared__ __align__(16) ushort_t Bsh_hi[64 * 40], Bsh_lo[64 * 40];

    f32x16 acc;
    #pragma unroll
    for (int i = 0; i < 16; ++i) acc[i] = 0.0f;

    const int sr = t >> 2, sc = t & 3;   // staging: 64 rows x 4 chunks of 16B

    for (int k0 = 0; k0 < DM; k0 += 32) {
        __syncthreads();
        *reinterpret_cast<uint4*>(&Ash_hi[sr * 40 + 8 * sc]) =
            *reinterpret_cast<const uint4*>(&x_hi[(size_t)(m0 + sr) * DM + k0 + 8 * sc]);
        *reinterpret_cast<uint4*>(&Ash_lo[sr * 40 + 8 * sc]) =
            *reinterpret_cast<const uint4*>(&x_lo[(size_t)(m0 + sr) * DM + k0 + 8 * sc]);
        *reinterpret_cast<uint4*>(&Bsh_hi[sr * 40 + 8 * sc]) =
            *reinterpret_cast<const uint4*>(&bt_hi[(size_t)(n0 + sr) * DM + k0 + 8 * sc]);
        *reinterpret_cast<uint4*>(&Bsh_lo[sr * 40 + 8 * sc]) =
            *reinterpret_cast<const uint4*>(&bt_lo[(size_t)(n0 + sr) * DM + k0 + 8 * sc]);
        __syncthreads();

        #pragma unroll
        for (int kp = 0; kp < 2; ++kp) {
            const int co = 8 * (hf + 2 * kp);
            short8 ah = *reinterpret_cast<const short8*>(&Ash_hi[(32 * wm + lq) * 40 + co]);
            short8 al = *reinterpret_cast<const short8*>(&Ash_lo[(32 * wm + lq) * 40 + co]);
            short8 bh = *reinterpret_cast<const short8*>(&Bsh_hi[(32 * wn + lq) * 40 + co]);
            short8 bl = *reinterpret_cast<const short8*>(&Bsh_lo[(32 * wn + lq) * 40 + co]);
            acc = MFMA32(ah, bh, acc);
            acc = MFMA32(ah, bl, acc);
            acc = MFMA32(al, bh, acc);
        }
    }

    const int nl = lq + 32 * wn;        // local n (== d, since n-block width 64 = head)
    const float bval = bias[n0 + nl];
    const int hh = n0 >> 6;             // head index

    #pragma unroll
    for (int r = 0; r < 16; ++r) {
        const int ml = (r & 3) + 8 * (r >> 2) + 4 * hf + 32 * wm;
        const float v = acc[r] + bval;
        ushort_t hi, lo; splitbf(v, hi, lo);
        if (z < 2) {
            ushort_t* dh = z == 0 ? q_hi : k_hi;
            ushort_t* dl = z == 0 ? q_lo : k_lo;
            const size_t o = ((size_t)hh * NTOK + m0 + ml) * DH + nl;
            dh[o] = hi; dl[o] = lo;
        } else {
            const size_t o = ((size_t)hh * DH + nl) * NTOK + m0 + ml;
            vT_hi[o] = hi; vT_lo[o] = lo;
        }
    }
}

// ------------------------------------------------------------ Wo GEMM ----
__global__ __launch_bounds__(256, 3)
void wo_gemm_mfma(const ushort_t* __restrict__ a_hi, const ushort_t* __restrict__ a_lo,
                  const ushort_t* __restrict__ bt_hi, const ushort_t* __restrict__ bt_lo,
                  const float* __restrict__ bias, float* __restrict__ out) {
    const int n0 = blockIdx.x * 64;
    const int m0 = blockIdx.y * 64;
    const int t  = threadIdx.x;
    const int wid = t >> 6, l = t & 63, hf = l >> 5, lq = l & 31;
    const int wm = wid >> 1, wn = wid & 1;

    __shared__ __align__(16) ushort_t Ash_hi[64 * 40], Ash_lo[64 * 40];
    __shared__ __align__(16) ushort_t Bsh_hi[64 * 40], Bsh_lo[64 * 40];

    f32x16 acc;
    #pragma unroll
    for (int i = 0; i < 16; ++i) acc[i] = 0.0f;

    const int sr = t >> 2, sc = t & 3;

    for (int k0 = 0; k0 < DM; k0 += 32) {
        __syncthreads();
        *reinterpret_cast<uint4*>(&Ash_hi[sr * 40 + 8 * sc]) =
            *reinterpret_cast<const uint4*>(&a_hi[(size_t)(m0 + sr) * DM + k0 + 8 * sc]);
        *reinterpret_cast<uint4*>(&Ash_lo[sr * 40 + 8 * sc]) =
            *reinterpret_cast<const uint4*>(&a_lo[(size_t)(m0 + sr) * DM + k0 + 8 * sc]);
        *reinterpret_cast<uint4*>(&Bsh_hi[sr * 40 + 8 * sc]) =
            *reinterpret_cast<const uint4*>(&bt_hi[(size_t)(n0 + sr) * DM + k0 + 8 * sc]);
        *reinterpret_cast<uint4*>(&Bsh_lo[sr * 40 + 8 * sc]) =
            *reinterpret_cast<const uint4*>(&bt_lo[(size_t)(n0 + sr) * DM + k0 + 8 * sc]);
        __syncthreads();

        #pragma unroll
        for (int kp = 0; kp < 2; ++kp) {
            const int co = 8 * (hf + 2 * kp);
            short8 ah = *reinterpret_cast<const short8*>(&Ash_hi[(32 * wm + lq) * 40 + co]);
            short8 al = *reinterpret_cast<const short8*>(&Ash_lo[(32 * wm + lq) * 40 + co]);
            short8 bh = *reinterpret_cast<const short8*>(&Bsh_hi[(32 * wn + lq) * 40 + co]);
            short8 bl = *reinterpret_cast<const short8*>(&Bsh_lo[(32 * wn + lq) * 40 + co]);
            acc = MFMA32(ah, bh, acc);
            acc = MFMA32(ah, bl, acc);
            acc = MFMA32(al, bh, acc);
        }
    }

    const int nl = lq + 32 * wn;
    const float bval = bias[n0 + nl];
    #pragma unroll
    for (int r = 0; r < 16; ++r) {
        const int ml = (r & 3) + 8 * (r >> 2) + 4 * hf + 32 * wm;
        out[(size_t)(m0 + ml) * DM + n0 + nl] = acc[r] + bval;
    }
}

// ----------------------------------------------------------- attention ----
// grid (16 qtiles, 8 heads, NSPLIT). QT=128 (4 waves x 32-q strips), KT=64.
// S^T = K·Q^T so each lane owns one q-row (col of D): in-register softmax.
// P split to bf16 hi/lo in-register; partner (lane^32) exchange builds PV A-frags.
__global__ __launch_bounds__(256, 2)
void attn_mfma(const ushort_t* __restrict__ q_hi, const ushort_t* __restrict__ q_lo,
               const ushort_t* __restrict__ k_hi, const ushort_t* __restrict__ k_lo,
               const ushort_t* __restrict__ vT_hi, const ushort_t* __restrict__ vT_lo,
               const unsigned char* __restrict__ bins_g, const float* __restrict__ z_table,
               float* __restrict__ po, float* __restrict__ pm, float* __restrict__ pl) {
    const int hd = blockIdx.y;
    const int q0 = blockIdx.x * 128;
    const int zs = blockIdx.z;
    const int t  = threadIdx.x;
    const int wid = t >> 6, l = t & 63, hf = l >> 5, lq = l & 31;
    const int qs = q0 + 32 * wid;          // wave's q strip

    // K rows [kt][d], V^T rows [d][kt]: 64 x 64 bf16, row stride 72 ushort (144 B)
    __shared__ __align__(16) ushort_t Ksh_hi[64 * 72], Ksh_lo[64 * 72];
    __shared__ __align__(16) ushort_t Vsh_hi[64 * 72], Vsh_lo[64 * 72];
    __shared__ __align__(16) unsigned char Bsh[128 * 80];   // bins, row stride 80 B

    const float ztab = z_table[(l & 15) * NH + hd];  // per-16-lane replicated table

    // Q B-frags in registers (col = lq -> q = qs+lq, k-slot d = 8*hf + j + 16*kp)
    short8 qf_hi[4], qf_lo[4];
    #pragma unroll
    for (int kp = 0; kp < 4; ++kp) {
        const size_t o = ((size_t)hd * NTOK + qs + lq) * DH + 8 * hf + 16 * kp;
        qf_hi[kp] = *reinterpret_cast<const short8*>(&q_hi[o]);
        qf_lo[kp] = *reinterpret_cast<const short8*>(&q_lo[o]);
    }

    float m_run = -1e30f, l_run = 0.0f;
    f32x16 oacc0, oacc1;
    #pragma unroll
    for (int i = 0; i < 16; ++i) { oacc0[i] = 0.0f; oacc1[i] = 0.0f; }

    const float scale = 0.125f;
    const int kbase = zs * KPS;

    for (int kt8 = 0; kt8 < KPS / 64; ++kt8) {
        const int ktb = kbase + kt8 * 64;
        __syncthreads();
        // -- stage K, V^T (hi/lo), bins
        #pragma unroll
        for (int i = 0; i < 2; ++i) {
            const int idx = t + 256 * i;
            const int r = idx >> 3, c = idx & 7;
            const size_t kg = ((size_t)hd * NTOK + ktb + r) * DH + 8 * c;
            const size_t vg = ((size_t)hd * DH + r) * NTOK + ktb + 8 * c;
            *reinterpret_cast<uint4*>(&Ksh_hi[r * 72 + 8 * c]) =
                *reinterpret_cast<const uint4*>(&k_hi[kg]);
            *reinterpret_cast<uint4*>(&Ksh_lo[r * 72 + 8 * c]) =
                *reinterpret_cast<const uint4*>(&k_lo[kg]);
            *reinterpret_cast<uint4*>(&Vsh_hi[r * 72 + 8 * c]) =
                *reinterpret_cast<const uint4*>(&vT_hi[vg]);
            *reinterpret_cast<uint4*>(&Vsh_lo[r * 72 + 8 * c]) =
                *reinterpret_cast<const uint4*>(&vT_lo[vg]);
        }
        #pragma unroll
        for (int i = 0; i < 2; ++i) {
            const int idx = t + 256 * i;
            const int qr = idx >> 2, c = idx & 3;
            *reinterpret_cast<uint4*>(&Bsh[qr * 80 + 16 * c]) =
                *reinterpret_cast<const uint4*>(&bins_g[(size_t)(q0 + qr) * NTOK + ktb + 16 * c]);
        }
        __syncthreads();

        // -- S^T = K · Q^T  (A = K frag rows kt, B = Q frag cols q)
        f32x16 sacc0, sacc1;
        #pragma unroll
        for (int i = 0; i < 16; ++i) { sacc0[i] = 0.0f; sacc1[i] = 0.0f; }
        #pragma unroll
        for (int kp = 0; kp < 4; ++kp) {
            const int co = 8 * (hf + 2 * kp);
            short8 k0h = *reinterpret_cast<const short8*>(&Ksh_hi[lq * 72 + co]);
            short8 k0l = *reinterpret_cast<const short8*>(&Ksh_lo[lq * 72 + co]);
            short8 k1h = *reinterpret_cast<const short8*>(&Ksh_hi[(lq + 32) * 72 + co]);
            short8 k1l = *reinterpret_cast<const short8*>(&Ksh_lo[(lq + 32) * 72 + co]);
            sacc0 = MFMA32(k0h, qf_hi[kp], sacc0);
            sacc0 = MFMA32(k0h, qf_lo[kp], sacc0);
            sacc0 = MFMA32(k0l, qf_hi[kp], sacc0);
            sacc1 = MFMA32(k1h, qf_hi[kp], sacc1);
            sacc1 = MFMA32(k1h, qf_lo[kp], sacc1);
            sacc1 = MFMA32(k1l, qf_hi[kp], sacc1);
        }

        // -- scale + z-bias (lane owns q = qs+lq; reg r <-> kt = (r&3)+8(r>>2)+4hf+32t2)
        float sv[2][16];
        #pragma unroll
        for (int t2 = 0; t2 < 2; ++t2) {
            #pragma unroll
            for (int b = 0; b < 4; ++b) {
                const unsigned bw = *reinterpret_cast<const unsigned*>(
                    &Bsh[(32 * wid + lq) * 80 + 4 * (hf + 2 * b + 8 * t2)]);
                #pragma unroll
                for (int c = 0; c < 4; ++c) {
                    const int r = c + 4 * b;
                    const int src = (int)((bw >> (8 * c)) & 0xFF) | (l & 48);
                    const float bias = __shfl(ztab, src, 64);
                    const float sraw = (t2 == 0 ? sacc0[r] : sacc1[r]);
                    sv[t2][r] = sraw * scale + bias;
                }
            }
        }

        // -- online softmax (row spread across lane pair l, l^32)
        float tm = sv[0][0];
        #pragma unroll
        for (int t2 = 0; t2 < 2; ++t2)
            #pragma unroll
            for (int r = 0; r < 16; ++r) tm = fmaxf(tm, sv[t2][r]);
        tm = fmaxf(tm, __shfl_xor(tm, 32, 64));
        const float mn = fmaxf(m_run, tm);
        const float ef = __expf(m_run - mn);
        m_run = mn;

        float pv[2][16];
        float ts = 0.0f;
        #pragma unroll
        for (int t2 = 0; t2 < 2; ++t2)
            #pragma unroll
            for (int r = 0; r < 16; ++r) {
                const float p = __expf(sv[t2][r] - mn);
                pv[t2][r] = p;
                ts += p;
            }
        ts += __shfl_xor(ts, 32, 64);
        l_run = l_run * ef + ts;

        // -- rescale O accumulators (O-reg r belongs to q_loc = (r&3)+8(r>>2)+4hf)
        #pragma unroll
        for (int r = 0; r < 16; ++r) {
            const int qloc = (r & 3) + 8 * (r >> 2) + 4 * hf;
            const float efr = __shfl(ef, qloc | (l & 32), 64);
            oacc0[r] *= efr;
            oacc1[r] *= efr;
        }

        // -- pack P to bf16 hi/lo and build PV A-frags (partner exchange)
        unsigned phi[2][8], plo[2][8];
        #pragma unroll
        for (int t2 = 0; t2 < 2; ++t2)
            #pragma unroll
            for (int i = 0; i < 8; ++i) {
                ushort_t ha, la, hb, lb;
                splitbf(pv[t2][2 * i],     ha, la);
                splitbf(pv[t2][2 * i + 1], hb, lb);
                phi[t2][i] = (unsigned)ha | ((unsigned)hb << 16);
                plo[t2][i] = (unsigned)la | ((unsigned)lb << 16);
            }

        FragU paf_hi[2][2], paf_lo[2][2];
        #pragma unroll
        for (int t2 = 0; t2 < 2; ++t2)
            #pragma unroll
            for (int e = 0; e < 2; ++e) {
                {
                    const unsigned pA0 = phi[t2][4 * e], pA1 = phi[t2][4 * e + 1];
                    const unsigned pB0 = phi[t2][4 * e + 2], pB1 = phi[t2][4 * e + 3];
                    const unsigned s0 = hf ? pA0 : pB0, s1 = hf ? pA1 : pB1;
                    const unsigned r0 = (unsigned)__shfl_xor((int)s0, 32, 64);
                    const unsigned r1 = (unsigned)__shfl_xor((int)s1, 32, 64);
                    paf_hi[t2][e].u[0] = hf ? r0 : pA0;
                    paf_hi[t2][e].u[1] = hf ? r1 : pA1;
                    paf_hi[t2][e].u[2] = hf ? pB0 : r0;
                    paf_hi[t2][e].u[3] = hf ? pB1 : r1;
                }
                {
                    const unsigned pA0 = plo[t2][4 * e], pA1 = plo[t2][4 * e + 1];
                    const unsigned pB0 = plo[t2][4 * e + 2], pB1 = plo[t2][4 * e + 3];
                    const unsigned s0 = hf ? pA0 : pB0, s1 = hf ? pA1 : pB1;
                    const unsigned r0 = (unsigned)__shfl_xor((int)s0, 32, 64);
                    const unsigned r1 = (unsigned)__shfl_xor((int)s1, 32, 64);
                    paf_lo[t2][e].u[0] = hf ? r0 : pA0;
                    paf_lo[t2][e].u[1] = hf ? r1 : pA1;
                    paf_lo[t2][e].u[2] = hf ? pB0 : r0;
                    paf_lo[t2][e].u[3] = hf ? pB1 : r1;
                }
            }

        // -- O += P · V   (A = P frag, B = V^T frag; kp -> kt chunk 16*kp)
        #pragma unroll
        for (int kp = 0; kp < 4; ++kp) {
            const int t2 = kp >> 1, e = kp & 1;
            const int co = 8 * (hf + 2 * kp);
            short8 v0h = *reinterpret_cast<const short8*>(&Vsh_hi[lq * 72 + co]);
            short8 v0l = *reinterpret_cast<const short8*>(&Vsh_lo[lq * 72 + co]);
            oacc0 = MFMA32(paf_hi[t2][e].s, v0h, oacc0);
            oacc0 = MFMA32(paf_hi[t2][e].s, v0l, oacc0);
            oacc0 = MFMA32(paf_lo[t2][e].s, v0h, oacc0);
            short8 v1h = *reinterpret_cast<const short8*>(&Vsh_hi[(lq + 32) * 72 + co]);
            short8 v1l = *reinterpret_cast<const short8*>(&Vsh_lo[(lq + 32) * 72 + co]);
            oacc1 = MFMA32(paf_hi[t2][e].s, v1h, oacc1);
            oacc1 = MFMA32(paf_hi[t2][e].s, v1l, oacc1);
            oacc1 = MFMA32(paf_lo[t2][e].s, v1h, oacc1);
        }
    }

    // -- epilogue: unnormalized partial O + (m, l)
    #pragma unroll
    for (int r = 0; r < 16; ++r) {
        const int qloc = (r & 3) + 8 * (r >> 2) + 4 * hf;
        const size_t row = ((size_t)(zs * NH + hd) * NTOK + qs + qloc) * DH;
        po[row + lq]      = oacc0[r];
        po[row + lq + 32] = oacc1[r];
    }
    if (hf == 0) {
        const size_t row = (size_t)(zs * NH + hd) * NTOK + qs + lq;
        pm[row] = m_run;
        pl[row] = l_run;
    }
}

// --------------------------------------------------------------- merge ----
__global__ __launch_bounds__(256)
void merge_kernel(const float* __restrict__ po, const float* __restrict__ pm,
                  const float* __restrict__ pl,
                  ushort_t* __restrict__ o_hi, ushort_t* __restrict__ o_lo) {
    const int idx = blockIdx.x * 256 + threadIdx.x;   // 262144 total
    const int d4 = (idx & 15) * 4;
    const int q  = (idx >> 4) & (NTOK - 1);
    const int hh = idx >> 15;

    float ms[NSPLIT];
    float M = -1e30f;
    #pragma unroll
    for (int s = 0; s < NSPLIT; ++s) {
        ms[s] = pm[((size_t)s * NH + hh) * NTOK + q];
        M = fmaxf(M, ms[s]);
    }
    float L = 0.0f;
    float4 o = make_float4(0.f, 0.f, 0.f, 0.f);
    #pragma unroll
    for (int s = 0; s < NSPLIT; ++s) {
        const float w = __expf(ms[s] - M);
        L += w * pl[((size_t)s * NH + hh) * NTOK + q];
        float4 p = *reinterpret_cast<const float4*>(
            po + (((size_t)s * NH + hh) * NTOK + q) * DH + d4);
        o.x += w * p.x; o.y += w * p.y; o.z += w * p.z; o.w += w * p.w;
    }
    const float inv = 1.0f / L;
    o.x *= inv; o.y *= inv; o.z *= inv; o.w *= inv;

    ushort_t h4[4], l4[4];
    splitbf(o.x, h4[0], l4[0]); splitbf(o.y, h4[1], l4[1]);
    splitbf(o.z, h4[2], l4[2]); splitbf(o.w, h4[3], l4[3]);
    const size_t oo = (size_t)q * DM + hh * DH + d4;
    *reinterpret_cast<ushort4*>(o_hi + oo) = make_ushort4(h4[0], h4[1], h4[2], h4[3]);
    *reinterpret_cast<ushort4*>(o_lo + oo) = make_ushort4(l4[0], l4[1], l4[2], l4[3]);
}

// --------------------------------------------------------------- launch ----
extern "C" void kernel_launch(void* const* d_in, const int* in_sizes, int n_in,
                              void* d_out, int out_size, void* d_ws, size_t ws_size,
                              hipStream_t stream) {
    const float* x        = (const float*)d_in[0];
    const float* z_matrix = (const float*)d_in[1];
    const float* Wq       = (const float*)d_in[2];
    const float* bq       = (const float*)d_in[3];
    const float* Wk       = (const float*)d_in[4];
    const float* bk       = (const float*)d_in[5];
    const float* Wv       = (const float*)d_in[6];
    const float* bv       = (const float*)d_in[7];
    const float* Wo       = (const float*)d_in[8];
    const float* bo       = (const float*)d_in[9];
    const float* z_table  = (const float*)d_in[10];
    float* out            = (float*)d_out;

    // ---- workspace layout (40.5 MB) ----
    uint8_t* w = (uint8_t*)d_ws;
    const size_t MB = 1024 * 1024;
    ushort_t* x_hi  = (ushort_t*)(w + 0);        // 2 MB  (aliased by o_hi after qkv)
    ushort_t* x_lo  = (ushort_t*)(w + 2  * MB);  // 2 MB  (aliased by o_lo)
    ushort_t* wqt_hi= (ushort_t*)(w + 4  * MB);  // z-strided 1 MB blocks:
    ushort_t* wqt_lo= (ushort_t*)(w + 4  * MB + 512 * 1024);
    ushort_t* wkt_hi= (ushort_t*)(w + 5  * MB);
    ushort_t* wkt_lo= (ushort_t*)(w + 5  * MB + 512 * 1024);
    ushort_t* wvt_hi= (ushort_t*)(w + 6  * MB);
    ushort_t* wvt_lo= (ushort_t*)(w + 6  * MB + 512 * 1024);
    ushort_t* wot_hi= (ushort_t*)(w + 7  * MB);
    ushort_t* wot_lo= (ushort_t*)(w + 7  * MB + 512 * 1024);
    ushort_t* q_hi  = (ushort_t*)(w + 8  * MB);  // [8][2048][64] = 2 MB each
    ushort_t* q_lo  = (ushort_t*)(w + 10 * MB);
    ushort_t* k_hi  = (ushort_t*)(w + 12 * MB);
    ushort_t* k_lo  = (ushort_t*)(w + 14 * MB);
    ushort_t* vT_hi = (ushort_t*)(w + 16 * MB);  // [8][64][2048]
    ushort_t* vT_lo = (ushort_t*)(w + 18 * MB);
    unsigned char* bins = (unsigned char*)(w + 20 * MB);  // 4 MB
    float* po = (float*)(w + 24 * MB);           // [4][8][2048][64] f32 = 16 MB
    float* pm = (float*)(w + 40 * MB);           // 256 KB
    float* pl = (float*)(w + 40 * MB + 256 * 1024);
    ushort_t* o_hi = x_hi;                       // alias: x dead after qkv
    ushort_t* o_lo = x_lo;

    // 1) bins + input conversions (independent)
    bins_kernel<<<dim3(NTOK * NTOK / 4 / 256), dim3(256), 0, stream>>>(z_matrix, bins);
    prep_w<<<dim3(16, 16, 4), dim3(256), 0, stream>>>(Wq, Wk, Wv, Wo,
        (ushort_t*)(w + 4 * MB), (ushort_t*)(w + 4 * MB + 512 * 1024));
    conv_x<<<dim3(NTOK * DM / 4 / 256), dim3(256), 0, stream>>>(x, x_hi, x_lo);

    // 2) QKV projection (z-fused, 768 blocks)
    qkv_gemm_mfma<<<dim3(DM / 64, NTOK / 64, 3), dim3(256), 0, stream>>>(
        x_hi, x_lo,
        wqt_hi, wqt_lo, wkt_hi, wkt_lo, wvt_hi, wvt_lo,
        bq, bk, bv,
        q_hi, q_lo, k_hi, k_lo, vT_hi, vT_lo);

    // 3) attention (512 blocks)
    attn_mfma<<<dim3(NTOK / 128, NH, NSPLIT), dim3(256), 0, stream>>>(
        q_hi, q_lo, k_hi, k_lo, vT_hi, vT_lo, bins, z_table, po, pm, pl);

    // 4) merge partials -> o hi/lo
    merge_kernel<<<dim3(NH * NTOK * DH / 4 / 256), dim3(256), 0, stream>>>(
        po, pm, pl, o_hi, o_lo);

    // 5) output projection
    wo_gemm_mfma<<<dim3(DM / 64, NTOK / 64), dim3(256), 0, stream>>>(
        o_hi, o_lo, wot_hi, wot_lo, bo, out);
}